// Round 3
// baseline (4903.885 us; speedup 1.0000x reference)
//
#include <hip/hip_runtime.h>
#include <hip/hip_bf16.h>
#include <math.h>

// Problem constants (match reference)
#define RR 10
#define BB 8
#define NN 8192
#define HH 8
#define BN 65536            // BB*NN nodes per ROI
#define EE (1u << 20)       // directed edges per ROI = 2*B*EPAIR
#define KK 4096             // TopK ratio 0.5
#define NSUP 80             // B*R super nodes

// ---------------- edge pass 1: in-degree ----------------
__global__ void deg_kernel(const int* __restrict__ ei, float* __restrict__ deg) {
  unsigned idx = blockIdx.x * 256u + threadIdx.x;
  unsigned r = idx >> 20;
  unsigned e = idx & (EE - 1u);
  if (r >= RR) return;
  int d = ei[((size_t)r * 2u + 1u) * EE + e];
  atomicAdd(&deg[(size_t)r * BN + d], 1.0f);   // small-int adds: exact & order-free
}

// ---------------- edge pass 2: normalized scatter-add of h[src] ----------------
__global__ void agg_kernel(const int* __restrict__ ei,
                           const float* __restrict__ x,
                           const float* __restrict__ gcn_w,
                           const float* __restrict__ deg,
                           float* __restrict__ agg) {
  unsigned idx = blockIdx.x * 256u + threadIdx.x;
  unsigned r = idx >> 20;
  unsigned e = idx & (EE - 1u);
  if (r >= RR) return;
  const int* base = ei + (size_t)r * 2u * EE;
  int s = base[e];
  int d = base[EE + e];
  float degs = deg[(size_t)r * BN + s] + 1.0f;   // +1 = self loop
  float degd = deg[(size_t)r * BN + d] + 1.0f;
  float norm = rsqrtf(degs) * rsqrtf(degd);
  float4 xv = ((const float4*)x)[(size_t)r * BN + s];   // recompute h[src] from x (saves a 21MB h buffer)
  const float* w = gcn_w + r * 32;                      // [4][8], wave-uniform r -> scalar loads
  float* ap = agg + ((size_t)r * BN + d) * 8;
#pragma unroll
  for (int c = 0; c < 8; ++c) {
    float h = xv.x * w[c] + xv.y * w[8 + c] + xv.z * w[16 + c] + xv.w * w[24 + c];
    atomicAdd(&ap[c], h * norm);
  }
}

// ---------------- per-(ROI,patient): combine + graph-LN + score + exact topK + pools ----------------
__global__ __launch_bounds__(1024)
void roi_kernel(const float* __restrict__ x,
                const float* __restrict__ gcn_w,
                const float* __restrict__ gcn_b,
                const float* __restrict__ ln_w,
                const float* __restrict__ ln_b,
                const float* __restrict__ topk_w,
                const float* __restrict__ cen,
                const float* __restrict__ deg,
                float* __restrict__ hbuf,     // agg in -> hrelu -> hn (in place)
                float* __restrict__ feats) {
  const int r = blockIdx.x / BB;
  const int b = blockIdx.x % BB;
  const int tid = threadIdx.x;

  __shared__ float sarr[NN];       // 32 KB sort array
  __shared__ double dred[1024];    // 8 KB reduction
  __shared__ int tscan[1024];      // tie prefix-scan
  __shared__ float chanSum[8];
  __shared__ float fvSum[8];
  __shared__ int cntGt;

  if (tid < 8) { chanSum[tid] = 0.f; fvSum[tid] = 0.f; }
  if (tid == 0) cntGt = 0;

  float w[32], bg[8], lw[8], lb[8], wt[8];
#pragma unroll
  for (int i = 0; i < 32; ++i) w[i] = gcn_w[r * 32 + i];
  float wn2 = 0.f;
#pragma unroll
  for (int c = 0; c < 8; ++c) {
    bg[c] = gcn_b[r * 8 + c];
    lw[c] = ln_w[r * 8 + c];
    lb[c] = ln_b[r * 8 + c];
    wt[c] = topk_w[r * 8 + c];
    wn2 += wt[c] * wt[c];
  }
  const float invn = 1.0f / sqrtf(wn2);

  const float4* x4 = (const float4*)x + (size_t)r * BN + (size_t)b * NN;
  const float* degp = deg + (size_t)r * BN + (size_t)b * NN;
  float* hp = hbuf + ((size_t)r * BN + (size_t)b * NN) * 8;

  // Pass A: hrelu = relu(agg + h_self/deg + bias); fp64 LN stats (thread owns nodes [tid*8, tid*8+8))
  double s1 = 0.0, s2 = 0.0;
#pragma unroll
  for (int i = 0; i < 8; ++i) {
    int n = tid * 8 + i;
    float4 xv = x4[n];
    float invd = 1.0f / (degp[n] + 1.0f);
#pragma unroll
    for (int c = 0; c < 8; ++c) {
      float hs = xv.x * w[c] + xv.y * w[8 + c] + xv.z * w[16 + c] + xv.w * w[24 + c];
      float v = hp[n * 8 + c] + hs * invd + bg[c];
      v = fmaxf(v, 0.0f);
      hp[n * 8 + c] = v;
      s1 += v;
      s2 += (double)v * v;
    }
  }
  dred[tid] = s1;
  __syncthreads();
  for (int off = 512; off > 0; off >>= 1) {
    if (tid < off) dred[tid] += dred[tid + off];
    __syncthreads();
  }
  double tot1 = dred[0];
  __syncthreads();
  dred[tid] = s2;
  __syncthreads();
  for (int off = 512; off > 0; off >>= 1) {
    if (tid < off) dred[tid] += dred[tid + off];
    __syncthreads();
  }
  double tot2 = dred[0];
  const double M = (double)NN * HH;
  double mu = tot1 / M;
  double var = tot2 / M - mu * mu;
  float muf = (float)mu;
  float rstd = (float)(1.0 / sqrt(var + 1e-5));

  // Pass B: normalize (in place), per-channel sums (res), scores
  float ch[8] = {0, 0, 0, 0, 0, 0, 0, 0};
  float sv[8];
#pragma unroll
  for (int i = 0; i < 8; ++i) {
    int n = tid * 8 + i;
    float pre = 0.f;
#pragma unroll
    for (int c = 0; c < 8; ++c) {
      float v = hp[n * 8 + c];
      float hn = (v - muf) * rstd * lw[c] + lb[c];
      hp[n * 8 + c] = hn;
      ch[c] += hn;
      pre += hn * wt[c];
    }
    float s = tanhf(pre * invn);
    sv[i] = s;
    sarr[n] = s;
  }
#pragma unroll
  for (int c = 0; c < 8; ++c) atomicAdd(&chanSum[c], ch[c]);
  __syncthreads();

  // Bitonic sort ascending (N = 8192)
  for (int k = 2; k <= NN; k <<= 1) {
    for (int j = k >> 1; j > 0; j >>= 1) {
      for (int i = tid; i < NN; i += 1024) {
        int ixj = i ^ j;
        if (ixj > i) {
          float a = sarr[i], b2 = sarr[ixj];
          bool up = ((i & k) == 0);
          if ((a > b2) == up) { sarr[i] = b2; sarr[ixj] = a; }
        }
      }
      __syncthreads();
    }
  }
  float tau = sarr[NN - KK];   // K-th largest

  // count strictly-greater; tie-break lowest-index-first (matches lax.top_k)
  int cg = 0, ct = 0;
#pragma unroll
  for (int i = 0; i < 8; ++i) {
    if (sv[i] > tau) cg++;
    else if (sv[i] == tau) ct++;
  }
  atomicAdd(&cntGt, cg);
  tscan[tid] = ct;
  __syncthreads();
  if (tid == 0) {
    int run = 0;
    for (int t = 0; t < 1024; ++t) { int tmp = tscan[t]; tscan[t] = run; run += tmp; }
  }
  __syncthreads();
  int quota = KK - cntGt;
  int rank = tscan[tid];
  float fva[8] = {0, 0, 0, 0, 0, 0, 0, 0};
#pragma unroll
  for (int i = 0; i < 8; ++i) {
    bool inc = sv[i] > tau;
    if (!inc && sv[i] == tau) { inc = (rank < quota); rank++; }
    if (inc) {
      int n = tid * 8 + i;
#pragma unroll
      for (int c = 0; c < 8; ++c) fva[c] += hp[n * 8 + c] * sv[i];
    }
  }
#pragma unroll
  for (int c = 0; c < 8; ++c) atomicAdd(&fvSum[c], fva[c]);
  __syncthreads();

  size_t fo = (size_t)(r * BB + b) * 19;
  if (tid < 8) {
    feats[fo + tid] = chanSum[tid] / (float)NN;        // res = mean over nodes
    feats[fo + 8 + tid] = fvSum[tid] / (float)KK;      // fv  = mean over selected
  }
  if (tid >= 16 && tid < 19) {
    feats[fo + tid] = cen[(size_t)(r * BB + b) * 3 + (tid - 16)];
  }
}

// ---------------- super graph: GAT1 -> LN -> GAT2 -> LN -> pool -> linear ----------------
__global__ __launch_bounds__(256)
void super_kernel(const float* __restrict__ feats,
                  const float* __restrict__ W1, const float* __restrict__ as1,
                  const float* __restrict__ ad1, const float* __restrict__ b1,
                  const float* __restrict__ lnw1, const float* __restrict__ lnb1,
                  const float* __restrict__ W2, const float* __restrict__ as2,
                  const float* __restrict__ ad2, const float* __restrict__ b2,
                  const float* __restrict__ lnw2, const float* __restrict__ lnb2,
                  const float* __restrict__ linw, const float* __restrict__ linb,
                  float* __restrict__ out) {
  __shared__ float sx[NSUP * 19];
  __shared__ float h1[NSUP * 64];
  __shared__ float x1[NSUP * 64];
  __shared__ float es1[NSUP * 4], ed1[NSUP * 4];
  __shared__ float h2[NSUP * 16], x2[NSUP * 16];
  __shared__ float es2[NSUP], ed2[NSUP];
  __shared__ float stat[16];
  const int tid = threadIdx.x;

  // load super_x: node n = b*R + r <- feats[r][b][:]
  for (int i = tid; i < NSUP * 19; i += 256) {
    int n = i / 19, c = i % 19;
    int bb = n / RR, rr = n % RR;
    sx[i] = feats[(size_t)(rr * BB + bb) * 19 + c];
  }
  __syncthreads();
  // h1 = sx @ W1 (no bias pre-attention)
  for (int p = tid; p < NSUP * 64; p += 256) {
    int n = p / 64, j = p % 64;
    float acc = 0.f;
    for (int k2 = 0; k2 < 19; ++k2) acc += sx[n * 19 + k2] * W1[k2 * 64 + j];
    h1[p] = acc;
  }
  __syncthreads();
  for (int p = tid; p < NSUP * 4; p += 256) {
    int n = p / 4, hd = p % 4;
    float a = 0.f, d2 = 0.f;
    for (int o = 0; o < 16; ++o) {
      float hv = h1[n * 64 + hd * 16 + o];
      a += hv * as1[hd * 16 + o];
      d2 += hv * ad1[hd * 16 + o];
    }
    es1[p] = a; ed1[p] = d2;
  }
  __syncthreads();
  // attention: hub (r==0) has self-loop only; others have {hub, self}
  for (int p = tid; p < NSUP * 64; p += 256) {
    int n = p / 64, j = p % 64, hd = j / 16;
    int rr = n % RR;
    float o;
    if (rr == 0) {
      o = h1[p];
    } else {
      int hub = n - rr;
      float eh = es1[hub * 4 + hd] + ed1[n * 4 + hd];
      float esf = es1[n * 4 + hd] + ed1[n * 4 + hd];
      eh = eh > 0.f ? eh : 0.2f * eh;
      esf = esf > 0.f ? esf : 0.2f * esf;
      float m = fmaxf(eh, esf);
      float wh = expf(eh - m), ws2 = expf(esf - m);
      o = (wh * h1[hub * 64 + j] + ws2 * h1[n * 64 + j]) / (wh + ws2);
    }
    float v = o + b1[j];
    x1[p] = v > 0.f ? v : expm1f(v);   // elu
  }
  __syncthreads();
  // graph-LN over (R*64) per patient
  if (tid < BB) {
    double m = 0.0, v2 = 0.0;
    for (int q = 0; q < RR * 64; ++q) {
      float val = x1[tid * RR * 64 + q];
      m += val; v2 += (double)val * val;
    }
    m /= (RR * 64.0); v2 = v2 / (RR * 64.0) - m * m;
    stat[tid] = (float)m;
    stat[8 + tid] = (float)(1.0 / sqrt(v2 + 1e-5));
  }
  __syncthreads();
  for (int p = tid; p < NSUP * 64; p += 256) {
    int n = p / 64, j = p % 64, bb = n / RR;
    x1[p] = (x1[p] - stat[bb]) * stat[8 + bb] * lnw1[j] + lnb1[j];
  }
  __syncthreads();
  // GAT2 (heads=1, oc=16)
  for (int p = tid; p < NSUP * 16; p += 256) {
    int n = p / 16, o = p % 16;
    float acc = 0.f;
    for (int j = 0; j < 64; ++j) acc += x1[n * 64 + j] * W2[j * 16 + o];
    h2[p] = acc;
  }
  __syncthreads();
  for (int n = tid; n < NSUP; n += 256) {
    float a = 0.f, d2 = 0.f;
    for (int o = 0; o < 16; ++o) {
      float hv = h2[n * 16 + o];
      a += hv * as2[o];
      d2 += hv * ad2[o];
    }
    es2[n] = a; ed2[n] = d2;
  }
  __syncthreads();
  for (int p = tid; p < NSUP * 16; p += 256) {
    int n = p / 16, o = p % 16;
    int rr = n % RR;
    float ov;
    if (rr == 0) ov = h2[p];
    else {
      int hub = n - rr;
      float eh = es2[hub] + ed2[n];
      float esf = es2[n] + ed2[n];
      eh = eh > 0.f ? eh : 0.2f * eh;
      esf = esf > 0.f ? esf : 0.2f * esf;
      float m = fmaxf(eh, esf);
      float wh = expf(eh - m), ws2 = expf(esf - m);
      ov = (wh * h2[hub * 16 + o] + ws2 * h2[p]) / (wh + ws2);
    }
    float v = ov + b2[o];
    x2[p] = v > 0.f ? v : expm1f(v);
  }
  __syncthreads();
  if (tid < BB) {
    double m = 0.0, v2 = 0.0;
    for (int q = 0; q < RR * 16; ++q) {
      float val = x2[tid * RR * 16 + q];
      m += val; v2 += (double)val * val;
    }
    m /= (RR * 16.0); v2 = v2 / (RR * 16.0) - m * m;
    stat[tid] = (float)m;
    stat[8 + tid] = (float)(1.0 / sqrt(v2 + 1e-5));
  }
  __syncthreads();
  for (int p = tid; p < NSUP * 16; p += 256) {
    int n = p / 16, o = p % 16, bb = n / RR;
    x2[p] = (x2[p] - stat[bb]) * stat[8 + bb] * lnw2[o] + lnb2[o];
  }
  __syncthreads();
  // pool over ROIs then linear head
  if (tid < BB * 2) {
    int bb = tid / 2, t = tid % 2;
    float acc = linb[t];
    for (int o = 0; o < 16; ++o) {
      float pm = 0.f;
      for (int rr = 0; rr < RR; ++rr) pm += x2[(bb * RR + rr) * 16 + o];
      pm /= (float)RR;
      acc += pm * linw[o * 2 + t];
    }
    out[bb * 2 + t] = acc;
  }
}

extern "C" void kernel_launch(void* const* d_in, const int* in_sizes, int n_in,
                              void* d_out, int out_size, void* d_ws, size_t ws_size,
                              hipStream_t stream) {
  const float* roi_x = (const float*)d_in[0];
  const int* ei = (const int*)d_in[1];
  const float* cen = (const float*)d_in[2];
  const float* gcn_w = (const float*)d_in[3];
  const float* gcn_b = (const float*)d_in[4];
  const float* ln_w = (const float*)d_in[5];
  const float* ln_b = (const float*)d_in[6];
  const float* topk_w = (const float*)d_in[7];
  const float* gat1_w = (const float*)d_in[8];
  const float* as1 = (const float*)d_in[9];
  const float* ad1 = (const float*)d_in[10];
  const float* b1 = (const float*)d_in[11];
  const float* lnw1 = (const float*)d_in[12];
  const float* lnb1 = (const float*)d_in[13];
  const float* W2 = (const float*)d_in[14];
  const float* as2 = (const float*)d_in[15];
  const float* ad2 = (const float*)d_in[16];
  const float* b2 = (const float*)d_in[17];
  const float* lnw2 = (const float*)d_in[18];
  const float* lnb2 = (const float*)d_in[19];
  const float* linw = (const float*)d_in[20];
  const float* linb = (const float*)d_in[21];
  float* out = (float*)d_out;

  // workspace layout (floats): agg/hn [R*BN*8] | deg [R*BN] | feats [R*B*19]  (~24 MB)
  float* ws = (float*)d_ws;
  float* agg = ws;
  float* deg = agg + (size_t)RR * BN * 8;
  float* feats = deg + (size_t)RR * BN;

  size_t zb = ((size_t)RR * BN * 8 + (size_t)RR * BN) * sizeof(float);
  hipMemsetAsync(d_ws, 0, zb, stream);   // fresh accumulators every call (ws is poisoned once)

  deg_kernel<<<RR * (EE / 256), 256, 0, stream>>>(ei, deg);
  agg_kernel<<<RR * (EE / 256), 256, 0, stream>>>(ei, roi_x, gcn_w, deg, agg);
  roi_kernel<<<RR * BB, 1024, 0, stream>>>(roi_x, gcn_w, gcn_b, ln_w, ln_b,
                                           topk_w, cen, deg, agg, feats);
  super_kernel<<<1, 256, 0, stream>>>(feats, gat1_w, as1, ad1, b1, lnw1, lnb1,
                                      W2, as2, ad2, b2, lnw2, lnb2, linw, linb, out);
}

// Round 4
// 950.696 us; speedup vs baseline: 5.1582x; 5.1582x over previous
//
#include <hip/hip_runtime.h>
#include <hip/hip_bf16.h>
#include <math.h>

// Problem constants (match reference)
#define RR 10
#define BB 8
#define NN 8192
#define HH 8
#define BN 65536            // BB*NN nodes per ROI
#define EE (1u << 20)       // directed edges per ROI = 2*B*EPAIR
#define EPB (EE / BB)       // 131072 directed edges per (ROI,patient), contiguous
#define KK 4096             // TopK ratio 0.5
#define NSUP 80             // B*R super nodes

// ---------------- pass 1: per-(r,b) in-degree via LDS histogram -> dis = rsqrt(deg+1) ----------------
__global__ __launch_bounds__(1024)
void deg_dis_kernel(const int* __restrict__ ei, float* __restrict__ dis) {
  const int r = blockIdx.x / BB;
  const int b = blockIdx.x % BB;
  const int tid = threadIdx.x;
  __shared__ int cnt[NN];                     // 32 KB
  for (int n = tid; n < NN; n += 1024) cnt[n] = 0;
  __syncthreads();
  const int* dstp = ei + ((size_t)r * 2u + 1u) * EE + (size_t)b * EPB;
#pragma unroll 4
  for (int e = tid; e < EPB; e += 1024) {
    int d = dstp[e];
    atomicAdd(&cnt[d & (NN - 1)], 1);         // node ids carry b*NN offset; mask to local
  }
  __syncthreads();
  float* dp = dis + (size_t)r * BN + (size_t)b * NN;
  for (int n = tid; n < NN; n += 1024) dp[n] = rsqrtf((float)cnt[n] + 1.0f);
}

// ---------------- pass 2: per-(r,b,half) LDS-private scatter-add of 4 channels ----------------
__global__ __launch_bounds__(1024)
void agg_half_kernel(const int* __restrict__ ei,
                     const float* __restrict__ x,
                     const float* __restrict__ gcn_w,
                     const float* __restrict__ dis,
                     float* __restrict__ agg) {
  const int rb = blockIdx.x >> 1;
  const int half = blockIdx.x & 1;
  const int r = rb / BB;
  const int b = rb % BB;
  const int tid = threadIdx.x;
  __shared__ float acc[NN * 4];               // 128 KB (guide-verified size)
  for (int i = tid; i < NN * 4; i += 1024) acc[i] = 0.f;

  // weight columns for channels [half*4, half*4+4): w4[in][c]
  float w4[4][4];
#pragma unroll
  for (int in = 0; in < 4; ++in)
#pragma unroll
    for (int c = 0; c < 4; ++c)
      w4[in][c] = gcn_w[r * 32 + in * 8 + half * 4 + c];
  __syncthreads();

  const int* base = ei + (size_t)r * 2u * EE;
  const int* srcp = base + (size_t)b * EPB;
  const int* dstp = base + EE + (size_t)b * EPB;
  const float* disr = dis + (size_t)r * BN;
  const float4* x4 = (const float4*)x + (size_t)r * BN;

#pragma unroll 2
  for (int e = tid; e < EPB; e += 1024) {
    int s = srcp[e];
    int d = dstp[e];
    float norm = disr[s] * disr[d];
    float4 xv = x4[s];
    int dl = (d & (NN - 1)) << 2;
#pragma unroll
    for (int c = 0; c < 4; ++c) {
      float h = xv.x * w4[0][c] + xv.y * w4[1][c] + xv.z * w4[2][c] + xv.w * w4[3][c];
      // XOR channel swizzle: spreads the 4-float node slot across all 32 banks
      atomicAdd(&acc[dl | ((c + dl) & 3)], h * norm);
    }
  }
  __syncthreads();

  // writeout: node n channels [half*4, half*4+4) as one float4 (unswizzle)
  float* ap = agg + ((size_t)r * BN + (size_t)b * NN) * 8 + half * 4;
  for (int n = tid; n < NN; n += 1024) {
    int nl = n << 2;
    float4 v;
    v.x = acc[nl | ((0 + nl) & 3)];
    v.y = acc[nl | ((1 + nl) & 3)];
    v.z = acc[nl | ((2 + nl) & 3)];
    v.w = acc[nl | ((3 + nl) & 3)];
    *(float4*)(ap + (size_t)n * 8) = v;
  }
}

// ---------------- per-(ROI,patient): combine + graph-LN + score + exact topK + pools ----------------
__global__ __launch_bounds__(1024)
void roi_kernel(const float* __restrict__ x,
                const float* __restrict__ gcn_w,
                const float* __restrict__ gcn_b,
                const float* __restrict__ ln_w,
                const float* __restrict__ ln_b,
                const float* __restrict__ topk_w,
                const float* __restrict__ cen,
                const float* __restrict__ dis,
                float* __restrict__ hbuf,     // agg in -> hrelu -> hn (in place)
                float* __restrict__ feats) {
  const int r = blockIdx.x / BB;
  const int b = blockIdx.x % BB;
  const int tid = threadIdx.x;

  __shared__ float sarr[NN];       // 32 KB sort array
  __shared__ double dred[1024];    // 8 KB reduction
  __shared__ int tscan[1024];      // tie prefix-scan
  __shared__ float chanSum[8];
  __shared__ float fvSum[8];
  __shared__ int cntGt;

  if (tid < 8) { chanSum[tid] = 0.f; fvSum[tid] = 0.f; }
  if (tid == 0) cntGt = 0;

  float w[32], bg[8], lw[8], lb[8], wt[8];
#pragma unroll
  for (int i = 0; i < 32; ++i) w[i] = gcn_w[r * 32 + i];
  float wn2 = 0.f;
#pragma unroll
  for (int c = 0; c < 8; ++c) {
    bg[c] = gcn_b[r * 8 + c];
    lw[c] = ln_w[r * 8 + c];
    lb[c] = ln_b[r * 8 + c];
    wt[c] = topk_w[r * 8 + c];
    wn2 += wt[c] * wt[c];
  }
  const float invn = 1.0f / sqrtf(wn2);

  const float4* x4 = (const float4*)x + (size_t)r * BN + (size_t)b * NN;
  const float* disp = dis + (size_t)r * BN + (size_t)b * NN;
  float* hp = hbuf + ((size_t)r * BN + (size_t)b * NN) * 8;

  // Pass A: hrelu = relu(agg + h_self/deg + bias); fp64 LN stats (thread owns nodes [tid*8, tid*8+8))
  double s1 = 0.0, s2 = 0.0;
#pragma unroll
  for (int i = 0; i < 8; ++i) {
    int n = tid * 8 + i;
    float4 xv = x4[n];
    float ds = disp[n];
    float invd = ds * ds;          // = 1/(deg+1) up to rsqrt rounding
#pragma unroll
    for (int c = 0; c < 8; ++c) {
      float hs = xv.x * w[c] + xv.y * w[8 + c] + xv.z * w[16 + c] + xv.w * w[24 + c];
      float v = hp[n * 8 + c] + hs * invd + bg[c];
      v = fmaxf(v, 0.0f);
      hp[n * 8 + c] = v;
      s1 += v;
      s2 += (double)v * v;
    }
  }
  dred[tid] = s1;
  __syncthreads();
  for (int off = 512; off > 0; off >>= 1) {
    if (tid < off) dred[tid] += dred[tid + off];
    __syncthreads();
  }
  double tot1 = dred[0];
  __syncthreads();
  dred[tid] = s2;
  __syncthreads();
  for (int off = 512; off > 0; off >>= 1) {
    if (tid < off) dred[tid] += dred[tid + off];
    __syncthreads();
  }
  double tot2 = dred[0];
  const double M = (double)NN * HH;
  double mu = tot1 / M;
  double var = tot2 / M - mu * mu;
  float muf = (float)mu;
  float rstd = (float)(1.0 / sqrt(var + 1e-5));

  // Pass B: normalize (in place), per-channel sums (res), scores
  float ch[8] = {0, 0, 0, 0, 0, 0, 0, 0};
  float sv[8];
#pragma unroll
  for (int i = 0; i < 8; ++i) {
    int n = tid * 8 + i;
    float pre = 0.f;
#pragma unroll
    for (int c = 0; c < 8; ++c) {
      float v = hp[n * 8 + c];
      float hn = (v - muf) * rstd * lw[c] + lb[c];
      hp[n * 8 + c] = hn;
      ch[c] += hn;
      pre += hn * wt[c];
    }
    float s = tanhf(pre * invn);
    sv[i] = s;
    sarr[n] = s;
  }
#pragma unroll
  for (int c = 0; c < 8; ++c) atomicAdd(&chanSum[c], ch[c]);
  __syncthreads();

  // Bitonic sort ascending (N = 8192)
  for (int k = 2; k <= NN; k <<= 1) {
    for (int j = k >> 1; j > 0; j >>= 1) {
      for (int i = tid; i < NN; i += 1024) {
        int ixj = i ^ j;
        if (ixj > i) {
          float a = sarr[i], b2 = sarr[ixj];
          bool up = ((i & k) == 0);
          if ((a > b2) == up) { sarr[i] = b2; sarr[ixj] = a; }
        }
      }
      __syncthreads();
    }
  }
  float tau = sarr[NN - KK];   // K-th largest

  // count strictly-greater; tie-break lowest-index-first (matches lax.top_k)
  int cg = 0, ct = 0;
#pragma unroll
  for (int i = 0; i < 8; ++i) {
    if (sv[i] > tau) cg++;
    else if (sv[i] == tau) ct++;
  }
  atomicAdd(&cntGt, cg);
  tscan[tid] = ct;
  __syncthreads();
  if (tid == 0) {
    int run = 0;
    for (int t = 0; t < 1024; ++t) { int tmp = tscan[t]; tscan[t] = run; run += tmp; }
  }
  __syncthreads();
  int quota = KK - cntGt;
  int rank = tscan[tid];
  float fva[8] = {0, 0, 0, 0, 0, 0, 0, 0};
#pragma unroll
  for (int i = 0; i < 8; ++i) {
    bool inc = sv[i] > tau;
    if (!inc && sv[i] == tau) { inc = (rank < quota); rank++; }
    if (inc) {
      int n = tid * 8 + i;
#pragma unroll
      for (int c = 0; c < 8; ++c) fva[c] += hp[n * 8 + c] * sv[i];
    }
  }
#pragma unroll
  for (int c = 0; c < 8; ++c) atomicAdd(&fvSum[c], fva[c]);
  __syncthreads();

  size_t fo = (size_t)(r * BB + b) * 19;
  if (tid < 8) {
    feats[fo + tid] = chanSum[tid] / (float)NN;        // res = mean over nodes
    feats[fo + 8 + tid] = fvSum[tid] / (float)KK;      // fv  = mean over selected
  }
  if (tid >= 16 && tid < 19) {
    feats[fo + tid] = cen[(size_t)(r * BB + b) * 3 + (tid - 16)];
  }
}

// ---------------- super graph: GAT1 -> LN -> GAT2 -> LN -> pool -> linear ----------------
__global__ __launch_bounds__(256)
void super_kernel(const float* __restrict__ feats,
                  const float* __restrict__ W1, const float* __restrict__ as1,
                  const float* __restrict__ ad1, const float* __restrict__ b1,
                  const float* __restrict__ lnw1, const float* __restrict__ lnb1,
                  const float* __restrict__ W2, const float* __restrict__ as2,
                  const float* __restrict__ ad2, const float* __restrict__ b2,
                  const float* __restrict__ lnw2, const float* __restrict__ lnb2,
                  const float* __restrict__ linw, const float* __restrict__ linb,
                  float* __restrict__ out) {
  __shared__ float sx[NSUP * 19];
  __shared__ float h1[NSUP * 64];
  __shared__ float x1[NSUP * 64];
  __shared__ float es1[NSUP * 4], ed1[NSUP * 4];
  __shared__ float h2[NSUP * 16], x2[NSUP * 16];
  __shared__ float es2[NSUP], ed2[NSUP];
  __shared__ float stat[16];
  const int tid = threadIdx.x;

  // load super_x: node n = b*R + r <- feats[r][b][:]
  for (int i = tid; i < NSUP * 19; i += 256) {
    int n = i / 19, c = i % 19;
    int bb = n / RR, rr = n % RR;
    sx[i] = feats[(size_t)(rr * BB + bb) * 19 + c];
  }
  __syncthreads();
  // h1 = sx @ W1 (no bias pre-attention)
  for (int p = tid; p < NSUP * 64; p += 256) {
    int n = p / 64, j = p % 64;
    float acc = 0.f;
    for (int k2 = 0; k2 < 19; ++k2) acc += sx[n * 19 + k2] * W1[k2 * 64 + j];
    h1[p] = acc;
  }
  __syncthreads();
  for (int p = tid; p < NSUP * 4; p += 256) {
    int n = p / 4, hd = p % 4;
    float a = 0.f, d2 = 0.f;
    for (int o = 0; o < 16; ++o) {
      float hv = h1[n * 64 + hd * 16 + o];
      a += hv * as1[hd * 16 + o];
      d2 += hv * ad1[hd * 16 + o];
    }
    es1[p] = a; ed1[p] = d2;
  }
  __syncthreads();
  // attention: hub (r==0) has self-loop only; others have {hub, self}
  for (int p = tid; p < NSUP * 64; p += 256) {
    int n = p / 64, j = p % 64, hd = j / 16;
    int rr = n % RR;
    float o;
    if (rr == 0) {
      o = h1[p];
    } else {
      int hub = n - rr;
      float eh = es1[hub * 4 + hd] + ed1[n * 4 + hd];
      float esf = es1[n * 4 + hd] + ed1[n * 4 + hd];
      eh = eh > 0.f ? eh : 0.2f * eh;
      esf = esf > 0.f ? esf : 0.2f * esf;
      float m = fmaxf(eh, esf);
      float wh = expf(eh - m), ws2 = expf(esf - m);
      o = (wh * h1[hub * 64 + j] + ws2 * h1[n * 64 + j]) / (wh + ws2);
    }
    float v = o + b1[j];
    x1[p] = v > 0.f ? v : expm1f(v);   // elu
  }
  __syncthreads();
  // graph-LN over (R*64) per patient
  if (tid < BB) {
    double m = 0.0, v2 = 0.0;
    for (int q = 0; q < RR * 64; ++q) {
      float val = x1[tid * RR * 64 + q];
      m += val; v2 += (double)val * val;
    }
    m /= (RR * 64.0); v2 = v2 / (RR * 64.0) - m * m;
    stat[tid] = (float)m;
    stat[8 + tid] = (float)(1.0 / sqrt(v2 + 1e-5));
  }
  __syncthreads();
  for (int p = tid; p < NSUP * 64; p += 256) {
    int n = p / 64, j = p % 64, bb = n / RR;
    x1[p] = (x1[p] - stat[bb]) * stat[8 + bb] * lnw1[j] + lnb1[j];
  }
  __syncthreads();
  // GAT2 (heads=1, oc=16)
  for (int p = tid; p < NSUP * 16; p += 256) {
    int n = p / 16, o = p % 16;
    float acc = 0.f;
    for (int j = 0; j < 64; ++j) acc += x1[n * 64 + j] * W2[j * 16 + o];
    h2[p] = acc;
  }
  __syncthreads();
  for (int n = tid; n < NSUP; n += 256) {
    float a = 0.f, d2 = 0.f;
    for (int o = 0; o < 16; ++o) {
      float hv = h2[n * 16 + o];
      a += hv * as2[o];
      d2 += hv * ad2[o];
    }
    es2[n] = a; ed2[n] = d2;
  }
  __syncthreads();
  for (int p = tid; p < NSUP * 16; p += 256) {
    int n = p / 16, o = p % 16;
    int rr = n % RR;
    float ov;
    if (rr == 0) ov = h2[p];
    else {
      int hub = n - rr;
      float eh = es2[hub] + ed2[n];
      float esf = es2[n] + ed2[n];
      eh = eh > 0.f ? eh : 0.2f * eh;
      esf = esf > 0.f ? esf : 0.2f * esf;
      float m = fmaxf(eh, esf);
      float wh = expf(eh - m), ws2 = expf(esf - m);
      ov = (wh * h2[hub * 16 + o] + ws2 * h2[p]) / (wh + ws2);
    }
    float v = ov + b2[o];
    x2[p] = v > 0.f ? v : expm1f(v);
  }
  __syncthreads();
  if (tid < BB) {
    double m = 0.0, v2 = 0.0;
    for (int q = 0; q < RR * 16; ++q) {
      float val = x2[tid * RR * 16 + q];
      m += val; v2 += (double)val * val;
    }
    m /= (RR * 16.0); v2 = v2 / (RR * 16.0) - m * m;
    stat[tid] = (float)m;
    stat[8 + tid] = (float)(1.0 / sqrt(v2 + 1e-5));
  }
  __syncthreads();
  for (int p = tid; p < NSUP * 16; p += 256) {
    int n = p / 16, o = p % 16, bb = n / RR;
    x2[p] = (x2[p] - stat[bb]) * stat[8 + bb] * lnw2[o] + lnb2[o];
  }
  __syncthreads();
  // pool over ROIs then linear head
  if (tid < BB * 2) {
    int bb = tid / 2, t = tid % 2;
    float acc = linb[t];
    for (int o = 0; o < 16; ++o) {
      float pm = 0.f;
      for (int rr = 0; rr < RR; ++rr) pm += x2[(bb * RR + rr) * 16 + o];
      pm /= (float)RR;
      acc += pm * linw[o * 2 + t];
    }
    out[bb * 2 + t] = acc;
  }
}

extern "C" void kernel_launch(void* const* d_in, const int* in_sizes, int n_in,
                              void* d_out, int out_size, void* d_ws, size_t ws_size,
                              hipStream_t stream) {
  const float* roi_x = (const float*)d_in[0];
  const int* ei = (const int*)d_in[1];
  const float* cen = (const float*)d_in[2];
  const float* gcn_w = (const float*)d_in[3];
  const float* gcn_b = (const float*)d_in[4];
  const float* ln_w = (const float*)d_in[5];
  const float* ln_b = (const float*)d_in[6];
  const float* topk_w = (const float*)d_in[7];
  const float* gat1_w = (const float*)d_in[8];
  const float* as1 = (const float*)d_in[9];
  const float* ad1 = (const float*)d_in[10];
  const float* b1 = (const float*)d_in[11];
  const float* lnw1 = (const float*)d_in[12];
  const float* lnb1 = (const float*)d_in[13];
  const float* W2 = (const float*)d_in[14];
  const float* as2 = (const float*)d_in[15];
  const float* ad2 = (const float*)d_in[16];
  const float* b2 = (const float*)d_in[17];
  const float* lnw2 = (const float*)d_in[18];
  const float* lnb2 = (const float*)d_in[19];
  const float* linw = (const float*)d_in[20];
  const float* linb = (const float*)d_in[21];
  float* out = (float*)d_out;

  // workspace layout (floats): agg/hn [R*BN*8] | dis [R*BN] | feats [R*B*19]  (~24 MB)
  // All buffers fully written by kernels each call -> no memset needed.
  float* ws = (float*)d_ws;
  float* agg = ws;
  float* dis = agg + (size_t)RR * BN * 8;
  float* feats = dis + (size_t)RR * BN;

  deg_dis_kernel<<<RR * BB, 1024, 0, stream>>>(ei, dis);
  agg_half_kernel<<<RR * BB * 2, 1024, 0, stream>>>(ei, roi_x, gcn_w, dis, agg);
  roi_kernel<<<RR * BB, 1024, 0, stream>>>(roi_x, gcn_w, gcn_b, ln_w, ln_b,
                                           topk_w, cen, dis, agg, feats);
  super_kernel<<<1, 256, 0, stream>>>(feats, gat1_w, as1, ad1, b1, lnw1, lnb1,
                                      W2, as2, ad2, b2, lnw2, lnb2, linw, linb, out);
}